// Round 5
// baseline (1303.963 us; speedup 1.0000x reference)
//
#include <hip/hip_runtime.h>
#include <hip/hip_bf16.h>

// Bahdanau attention (R5):
//   q = dh @ Wq^T                                  (f32, tiny)
//   Wk -> bf16 (2 MB, ~2 us)
//   scores[b,s] = v . tanh(q[b] + Wk @ enc[b,s])   fused GEMM: BM=128 x BN=1024(all N) x BK=32,
//       16 waves (1024 thr), enc read ONCE as f32 (in-reg cvt), B via global_load_lds,
//       dbuf LDS 144KB, 2-phase pipeline (STAGE top, one fused vmcnt(0)+barrier per iter)
//   attn = softmax(mask ? scores : -1e9)
//   ctx[b,e] = sum_s attn[b,s]*enc[b,s,e]          (memory-bound, f32)

#define NB 32
#define SS 2048
#define HD 1024
#define HE 1024
#define MM (NB * SS)   // 65536 rows
#define NT 32          // K-tiles = HE/32

typedef float f32x4 __attribute__((ext_vector_type(4)));
typedef short bf16x8 __attribute__((ext_vector_type(8)));
typedef short short4v __attribute__((ext_vector_type(4)));

static __device__ __forceinline__ short f2bf(float f) {
    union { __hip_bfloat16 h; short s; } u;
    u.h = __float2bfloat16(f);
    return u.s;
}

// async global->LDS, 16B per lane; LDS dest = wave-uniform base + lane*16.
static __device__ __forceinline__ void gload16(const void* g, const void* l) {
    __builtin_amdgcn_global_load_lds(
        (const __attribute__((address_space(1))) void*)(uintptr_t)(g),
        (__attribute__((address_space(3))) void*)(unsigned)(uintptr_t)(l),
        16, 0, 0);
}

// ---------------- f32 -> bf16 conversion (Wk only, 1M elems) ----------------
__global__ __launch_bounds__(256) void cvt_bf16_kernel(const float* __restrict__ in,
                                                       short* __restrict__ out, int n8) {
    int i = blockIdx.x * 256 + threadIdx.x;
    const int stride = gridDim.x * 256;
    for (; i < n8; i += stride) {
        const f32x4 a = *(const f32x4*)(in + (long)i * 8);
        const f32x4 b = *(const f32x4*)(in + (long)i * 8 + 4);
        bf16x8 o;
        o[0] = f2bf(a[0]); o[1] = f2bf(a[1]); o[2] = f2bf(a[2]); o[3] = f2bf(a[3]);
        o[4] = f2bf(b[0]); o[5] = f2bf(b[1]); o[6] = f2bf(b[2]); o[7] = f2bf(b[3]);
        *(bf16x8*)(out + (long)i * 8) = o;
    }
}

// ---------------- q = dh @ Wq^T : one wave per output column d ----------------
__global__ __launch_bounds__(256) void qproj_kernel(const float* __restrict__ dh,
                                                    const float* __restrict__ Wq,
                                                    float* __restrict__ q) {
    const int wid  = threadIdx.x >> 6;
    const int lane = threadIdx.x & 63;
    const int d    = blockIdx.x * 4 + wid;
    const float* wrow = Wq + (long)d * HD + lane * 16;
    f32x4 w0 = *(const f32x4*)(wrow + 0);
    f32x4 w1 = *(const f32x4*)(wrow + 4);
    f32x4 w2 = *(const f32x4*)(wrow + 8);
    f32x4 w3 = *(const f32x4*)(wrow + 12);
    for (int b = 0; b < NB; ++b) {
        const float* drow = dh + b * HD + lane * 16;
        f32x4 d0 = *(const f32x4*)(drow + 0);
        f32x4 d1 = *(const f32x4*)(drow + 4);
        f32x4 d2 = *(const f32x4*)(drow + 8);
        f32x4 d3 = *(const f32x4*)(drow + 12);
        f32x4 s4 = w0 * d0 + w1 * d1 + w2 * d2 + w3 * d3;
        float dot = s4[0] + s4[1] + s4[2] + s4[3];
        #pragma unroll
        for (int off = 32; off > 0; off >>= 1)
            dot += __shfl_xor(dot, off, 64);
        if (lane == 0) q[b * HD + d] = dot;
    }
}

// ---------------- fused score GEMM: 128 rows x ALL 1024 cols per block ----------------
// A = enc rows (f32, read once, in-reg cvt to bf16); B = wkb (bf16, L2-resident,
// global_load_lds). 16 waves (2M x 8N), wave tile 64M x 128N: acc[4][8]. 32 K-iters.
__global__ __launch_bounds__(1024) void score_fused_kernel(const float* __restrict__ enc,
                                                           const short* __restrict__ wkb,
                                                           const float* __restrict__ qv,
                                                           const float* __restrict__ ven,
                                                           float* __restrict__ sp) {
    __shared__ __align__(16) short As[2][128 * 32];    // 2 x 8 KB
    __shared__ __align__(16) short Bs[2][1024 * 32];   // 2 x 64 KB

    const int tid  = threadIdx.x;
    const int lane = tid & 63;
    const int wid  = tid >> 6;            // 0..15
    const int wr   = wid >> 3;            // 0..1  (M half)
    const int wc   = wid & 7;             // 0..7  (N eighth)
    const long mbase = (long)blockIdx.x * 128;

    f32x4 acc[4][8];
    #pragma unroll
    for (int m = 0; m < 4; ++m)
        #pragma unroll
        for (int n = 0; n < 8; ++n)
            acc[m][n] = (f32x4){0.f, 0.f, 0.f, 0.f};

    // A staging: thread t -> row t>>3 (0..127), col (t&7)*4; one f32x4 -> cvt -> 8B ds_write
    const int arow = tid >> 3;
    const int acol = (tid & 7) * 4;
    const float* aptr = enc + (mbase + arow) * (long)HE + acol;
    const int aoff = arow * 32 + acol;    // shorts within As[buf]

    // B staging: 4096 16B-chunks; thread t covers c = j*1024 + t, j=0..3.
    // chunk c -> row c>>2 (0..1023), quarter c&3 (k-offset (c&3)*8 shorts). LDS linear.
    const int frow  = lane & 15;
    const int khalf = (lane >> 4) * 8;    // k-offset in shorts (0,8,16,24)

    // ---- prologue: stage tile 0 ----
    {
        f32x4 a = *(const f32x4*)(aptr);
        #pragma unroll
        for (int j = 0; j < 4; ++j) {
            const int c = j * 1024 + tid;
            gload16(wkb + (long)(c >> 2) * HE + (c & 3) * 8,
                    (short*)Bs[0] + (j * 1024 + wid * 64) * 8);
        }
        short4v av;
        av[0] = f2bf(a[0]); av[1] = f2bf(a[1]); av[2] = f2bf(a[2]); av[3] = f2bf(a[3]);
        *(short4v*)((short*)As[0] + aoff) = av;
        __syncthreads();
    }

    for (int kt = 0; kt < NT; ++kt) {
        const int cur = kt & 1;

        // stage next tile: A f32 load first (oldest in vmcnt queue -> cvt's wait
        // leaves B gloads in flight), then 4 B gloads into the other buffer
        f32x4 a;
        if (kt + 1 < NT) {
            a = *(const f32x4*)(aptr + (kt + 1) * 32);
            #pragma unroll
            for (int j = 0; j < 4; ++j) {
                const int c = j * 1024 + tid;
                gload16(wkb + (long)(c >> 2) * HE + (kt + 1) * 32 + (c & 3) * 8,
                        (short*)Bs[cur ^ 1] + (j * 1024 + wid * 64) * 8);
            }
        }

        // compute on current buffers
        bf16x8 af[4], bfr[8];
        #pragma unroll
        for (int m = 0; m < 4; ++m)
            af[m] = *(const bf16x8*)((const short*)As[cur] + (wr * 64 + m * 16 + frow) * 32 + khalf);
        #pragma unroll
        for (int n = 0; n < 8; ++n)
            bfr[n] = *(const bf16x8*)((const short*)Bs[cur] + (wc * 128 + n * 16 + frow) * 32 + khalf);
        #pragma unroll
        for (int m = 0; m < 4; ++m)
            #pragma unroll
            for (int n = 0; n < 8; ++n)
                acc[m][n] = __builtin_amdgcn_mfma_f32_16x16x32_bf16(af[m], bfr[n], acc[m][n], 0, 0, 0);

        if (kt + 1 < NT) {
            // cvt + write next A tile, then drain B gloads + LDS ops and sync
            short4v av;
            av[0] = f2bf(a[0]); av[1] = f2bf(a[1]); av[2] = f2bf(a[2]); av[3] = f2bf(a[3]);
            *(short4v*)((short*)As[cur ^ 1] + aoff) = av;
            asm volatile("s_waitcnt vmcnt(0) lgkmcnt(0)\n\ts_barrier" ::: "memory");
        }
    }

    // ---- epilogue: partial score = sum over this wave's 128 cols of v[c]*tanh(q[b,c]+k)
    // C/D layout: col = lane&15, row = (lane>>4)*4 + reg
    const int bb = (int)(mbase >> 11);
    float qq[8], vv[8];
    #pragma unroll
    for (int n = 0; n < 8; ++n) {
        const int c = wc * 128 + n * 16 + frow;
        qq[n] = qv[bb * HD + c];
        vv[n] = ven[c];
    }
    float p[4][4];
    #pragma unroll
    for (int m = 0; m < 4; ++m) {
        #pragma unroll
        for (int rg = 0; rg < 4; ++rg) {
            float s = 0.f;
            #pragma unroll
            for (int n = 0; n < 8; ++n) {
                const float x = acc[m][n][rg] + qq[n];
                const float e = __expf(2.f * x);
                const float t = 1.f - 2.f * __builtin_amdgcn_rcpf(e + 1.f);
                s += vv[n] * t;
            }
            #pragma unroll
            for (int msk = 1; msk <= 8; msk <<= 1)
                s += __shfl_xor(s, msk, 64);   // reduce over 16-lane col group
            p[m][rg] = s;
        }
    }
    if ((lane & 15) == 0) {
        const int g = lane >> 4;
        float* dst = sp + (long)wc * MM;   // 8 deterministic partial slots per row
        #pragma unroll
        for (int m = 0; m < 4; ++m)
            #pragma unroll
            for (int rg = 0; rg < 4; ++rg)
                dst[mbase + wr * 64 + m * 16 + g * 4 + rg] = p[m][rg];
    }
}

// ---------------- mask + softmax over S per batch ----------------
__global__ __launch_bounds__(256) void softmax_kernel(const float* __restrict__ sp,
                                                      const int* __restrict__ mask,
                                                      float* __restrict__ attn) {
    const int b = blockIdx.x;
    const int tid = threadIdx.x;
    const int lane = tid & 63;
    const int wid = tid >> 6;
    __shared__ float red[4];
    float sc[8];
    float mx = -3.0e38f;
    #pragma unroll
    for (int i = 0; i < 8; ++i) {
        const int s = tid + i * 256;
        float v = 0.f;
        #pragma unroll
        for (int k = 0; k < 8; ++k)
            v += sp[(long)k * MM + b * SS + s];
        if (mask[b * SS + s] == 0) v = -1e9f;
        sc[i] = v;
        mx = fmaxf(mx, v);
    }
    #pragma unroll
    for (int off = 32; off > 0; off >>= 1)
        mx = fmaxf(mx, __shfl_xor(mx, off, 64));
    if (lane == 0) red[wid] = mx;
    __syncthreads();
    mx = fmaxf(fmaxf(red[0], red[1]), fmaxf(red[2], red[3]));
    __syncthreads();
    float sum = 0.f;
    #pragma unroll
    for (int i = 0; i < 8; ++i) {
        const float e = __expf(sc[i] - mx);
        sc[i] = e;
        sum += e;
    }
    #pragma unroll
    for (int off = 32; off > 0; off >>= 1)
        sum += __shfl_xor(sum, off, 64);
    if (lane == 0) red[wid] = sum;
    __syncthreads();
    sum = red[0] + red[1] + red[2] + red[3];
    const float inv = 1.f / sum;
    #pragma unroll
    for (int i = 0; i < 8; ++i)
        attn[b * SS + tid + i * 256] = sc[i] * inv;
}

// ---------------- context: partial weighted sums over s-chunks (f32 enc) ----------------
__global__ __launch_bounds__(256) void ctx_partial_kernel(const float* __restrict__ enc,
                                                          const float* __restrict__ attn,
                                                          float* __restrict__ cp) {
    const int b = blockIdx.x >> 5;
    const int chunk = blockIdx.x & 31;
    const int tid = threadIdx.x;
    const float* ep = enc + ((long)b * SS + chunk * 64) * HE + tid * 4;
    const float* ap = attn + b * SS + chunk * 64;
    f32x4 acc = (f32x4){0.f, 0.f, 0.f, 0.f};
    #pragma unroll 4
    for (int s = 0; s < 64; ++s) {
        const float w = ap[s];
        const f32x4 v = *(const f32x4*)(ep + (long)s * HE);
        acc += w * v;
    }
    *(f32x4*)(cp + ((long)(b * 32 + chunk)) * HE + tid * 4) = acc;
}

__global__ __launch_bounds__(256) void ctx_reduce_kernel(const float* __restrict__ cp,
                                                         float* __restrict__ out) {
    const int o = blockIdx.x * 256 + threadIdx.x;
    const int b = o >> 10;
    const int e = o & 1023;
    float s = 0.f;
    #pragma unroll
    for (int c = 0; c < 32; ++c)
        s += cp[((long)(b * 32 + c)) * HE + e];
    out[o] = s;
}

extern "C" void kernel_launch(void* const* d_in, const int* in_sizes, int n_in,
                              void* d_out, int out_size, void* d_ws, size_t ws_size,
                              hipStream_t stream) {
    const float* dh   = (const float*)d_in[0];
    const float* enc  = (const float*)d_in[1];
    const int*   mask = (const int*)d_in[2];
    const float* Wq   = (const float*)d_in[3];
    const float* Wk   = (const float*)d_in[4];
    const float* Ve   = (const float*)d_in[5];

    float* out  = (float*)d_out;
    float* ctx  = out;
    float* attn = out + NB * HD;

    float* ws  = (float*)d_ws;
    float* wq_ = ws;                           // 32768 f
    float* sp  = ws + 32768;                   // 8 * 65536 f (2 MB)
    float* cp  = sp + 8 * (long)MM;            // 32*32*1024 f (4 MB)
    short* wkb = (short*)(cp + 32 * 32 * HE);  // 1M bf16 (2 MB)

    qproj_kernel<<<256, 256, 0, stream>>>(dh, Wq, wq_);
    cvt_bf16_kernel<<<512, 256, 0, stream>>>(Wk, wkb, HD * HE / 8);
    score_fused_kernel<<<512, 1024, 0, stream>>>(enc, wkb, wq_, Ve, sp);
    softmax_kernel<<<32, 256, 0, stream>>>(sp, mask, attn);
    ctx_partial_kernel<<<1024, 256, 0, stream>>>(enc, attn, cp);
    ctx_reduce_kernel<<<128, 256, 0, stream>>>(cp, ctx);
}

// Round 6
// 252.058 us; speedup vs baseline: 5.1733x; 5.1733x over previous
//
#include <hip/hip_runtime.h>
#include <hip/hip_bf16.h>

// Bahdanau attention (R6):
//   q = dh @ Wq^T                                  (f32, tiny)
//   Wk -> bf16 (2 MB)
//   scores[b,s] = v . tanh(q[b] + Wk @ enc[b,s])   fused GEMM: BM=128 x BN=512 x BK=32,
//       512 thr / 8 waves (2Mx4N, wave tile 64x128, acc[4][8]=128 VGPR, 2 waves/SIMD),
//       enc read once as f32 (in-reg cvt), B via global_load_lds from L2, LDS 80 KB dbuf,
//       2-phase pipeline, XCD swizzle pairs (mstrip, nt=0/1) on one XCD for A L2 reuse
//   attn = softmax(mask ? scores : -1e9)
//   ctx[b,e] = sum_s attn[b,s]*enc[b,s,e]          (memory-bound, f32)

#define NB 32
#define SS 2048
#define HD 1024
#define HE 1024
#define MM (NB * SS)   // 65536 rows
#define NT 32          // K-tiles = HE/32

typedef float f32x4 __attribute__((ext_vector_type(4)));
typedef short bf16x8 __attribute__((ext_vector_type(8)));
typedef short short4v __attribute__((ext_vector_type(4)));

static __device__ __forceinline__ short f2bf(float f) {
    union { __hip_bfloat16 h; short s; } u;
    u.h = __float2bfloat16(f);
    return u.s;
}

// async global->LDS, 16B per lane; LDS dest = wave-uniform base + lane*16.
static __device__ __forceinline__ void gload16(const void* g, const void* l) {
    __builtin_amdgcn_global_load_lds(
        (const __attribute__((address_space(1))) void*)(uintptr_t)(g),
        (__attribute__((address_space(3))) void*)(unsigned)(uintptr_t)(l),
        16, 0, 0);
}

// ---------------- f32 -> bf16 conversion (Wk only, 1M elems) ----------------
__global__ __launch_bounds__(256) void cvt_bf16_kernel(const float* __restrict__ in,
                                                       short* __restrict__ out, int n8) {
    int i = blockIdx.x * 256 + threadIdx.x;
    const int stride = gridDim.x * 256;
    for (; i < n8; i += stride) {
        const f32x4 a = *(const f32x4*)(in + (long)i * 8);
        const f32x4 b = *(const f32x4*)(in + (long)i * 8 + 4);
        bf16x8 o;
        o[0] = f2bf(a[0]); o[1] = f2bf(a[1]); o[2] = f2bf(a[2]); o[3] = f2bf(a[3]);
        o[4] = f2bf(b[0]); o[5] = f2bf(b[1]); o[6] = f2bf(b[2]); o[7] = f2bf(b[3]);
        *(bf16x8*)(out + (long)i * 8) = o;
    }
}

// ---------------- q = dh @ Wq^T : one wave per output column d ----------------
__global__ __launch_bounds__(256) void qproj_kernel(const float* __restrict__ dh,
                                                    const float* __restrict__ Wq,
                                                    float* __restrict__ q) {
    const int wid  = threadIdx.x >> 6;
    const int lane = threadIdx.x & 63;
    const int d    = blockIdx.x * 4 + wid;
    const float* wrow = Wq + (long)d * HD + lane * 16;
    f32x4 w0 = *(const f32x4*)(wrow + 0);
    f32x4 w1 = *(const f32x4*)(wrow + 4);
    f32x4 w2 = *(const f32x4*)(wrow + 8);
    f32x4 w3 = *(const f32x4*)(wrow + 12);
    for (int b = 0; b < NB; ++b) {
        const float* drow = dh + b * HD + lane * 16;
        f32x4 d0 = *(const f32x4*)(drow + 0);
        f32x4 d1 = *(const f32x4*)(drow + 4);
        f32x4 d2 = *(const f32x4*)(drow + 8);
        f32x4 d3 = *(const f32x4*)(drow + 12);
        f32x4 s4 = w0 * d0 + w1 * d1 + w2 * d2 + w3 * d3;
        float dot = s4[0] + s4[1] + s4[2] + s4[3];
        #pragma unroll
        for (int off = 32; off > 0; off >>= 1)
            dot += __shfl_xor(dot, off, 64);
        if (lane == 0) q[b * HD + d] = dot;
    }
}

// ---------------- fused score GEMM: 128 rows x 512 cols per block ----------------
__global__ __launch_bounds__(512, 2) void score_fused_kernel(const float* __restrict__ enc,
                                                             const short* __restrict__ wkb,
                                                             const float* __restrict__ qv,
                                                             const float* __restrict__ ven,
                                                             float* __restrict__ sp) {
    __shared__ __align__(16) short As[2][128 * 32];   // 2 x 8 KB
    __shared__ __align__(16) short Bs[2][512 * 32];   // 2 x 32 KB

    // XCD swizzle: 8 consecutive bids -> one XCD; within an XCD, slot pairs
    // (2j, 2j+1) = (mstrip, nt=0/1) run adjacently -> A K-slices shared in XCD L2.
    const int bid    = blockIdx.x;
    const int xcd    = bid & 7;
    const int slot   = bid >> 3;               // 0..127
    const int mstrip = xcd * 64 + (slot >> 1); // 0..511
    const int nt     = slot & 1;               // N half

    const int tid  = threadIdx.x;
    const int lane = tid & 63;
    const int wid  = tid >> 6;            // 0..7
    const int wr   = wid >> 2;            // 0..1  (M half)
    const int wc   = wid & 3;             // 0..3  (N quarter of the half)
    const long mbase = (long)mstrip * 128;
    const int  nbase = nt * 512;

    f32x4 acc[4][8];
    #pragma unroll
    for (int m = 0; m < 4; ++m)
        #pragma unroll
        for (int n = 0; n < 8; ++n)
            acc[m][n] = (f32x4){0.f, 0.f, 0.f, 0.f};

    // A staging: 1024 f32x4-chunks/K-step; thread t covers c = t and t+512.
    // chunk c -> row c>>3 (0..127), col (c&7)*4
    const float* aptr0 = enc + (mbase + (tid >> 3)) * (long)HE + (tid & 7) * 4;
    const float* aptr1 = aptr0 + 64 * (long)HE;          // chunk t+512 -> row +64
    const int aoff0 = (tid >> 3) * 32 + (tid & 7) * 4;   // shorts within As[buf]
    const int aoff1 = aoff0 + 64 * 32;

    const int frow  = lane & 15;
    const int khalf = (lane >> 4) * 8;    // k-offset in shorts (0,8,16,24)

    // B staging: 2048 16B-chunks; thread t covers c = j*512 + t, j=0..3.
    // chunk c -> B-row c>>2 (0..511), k-quarter c&3; LDS linear [512][32].
    #define BSTAGE(buf, kt)                                                     \
        do {                                                                    \
            _Pragma("unroll")                                                   \
            for (int j = 0; j < 4; ++j) {                                       \
                const int c = j * 512 + tid;                                    \
                gload16(wkb + ((long)(nbase + (c >> 2))) * HE + (kt) * 32 + (c & 3) * 8, \
                        (short*)Bs[buf] + (j * 512 + wid * 64) * 8);            \
            }                                                                   \
        } while (0)

    // ---- prologue: stage tile 0 ----
    {
        f32x4 a0 = *(const f32x4*)(aptr0);
        f32x4 a1 = *(const f32x4*)(aptr1);
        BSTAGE(0, 0);
        short4v v0, v1;
        v0[0] = f2bf(a0[0]); v0[1] = f2bf(a0[1]); v0[2] = f2bf(a0[2]); v0[3] = f2bf(a0[3]);
        v1[0] = f2bf(a1[0]); v1[1] = f2bf(a1[1]); v1[2] = f2bf(a1[2]); v1[3] = f2bf(a1[3]);
        *(short4v*)((short*)As[0] + aoff0) = v0;
        *(short4v*)((short*)As[0] + aoff1) = v1;
        __syncthreads();
    }

    for (int kt = 0; kt < NT; ++kt) {
        const int cur = kt & 1;

        // stage next tile: A f32 loads first (oldest in vmcnt queue -> the cvt's
        // implicit wait leaves the 4 younger B gloads in flight), then B gloads.
        f32x4 a0, a1;
        if (kt + 1 < NT) {
            a0 = *(const f32x4*)(aptr0 + (kt + 1) * 32);
            a1 = *(const f32x4*)(aptr1 + (kt + 1) * 32);
            BSTAGE(cur ^ 1, kt + 1);
        }

        // compute on current buffers
        bf16x8 af[4], bfr[8];
        #pragma unroll
        for (int m = 0; m < 4; ++m)
            af[m] = *(const bf16x8*)((const short*)As[cur] + (wr * 64 + m * 16 + frow) * 32 + khalf);
        #pragma unroll
        for (int n = 0; n < 8; ++n)
            bfr[n] = *(const bf16x8*)((const short*)Bs[cur] + (wc * 128 + n * 16 + frow) * 32 + khalf);
        #pragma unroll
        for (int m = 0; m < 4; ++m)
            #pragma unroll
            for (int n = 0; n < 8; ++n)
                acc[m][n] = __builtin_amdgcn_mfma_f32_16x16x32_bf16(af[m], bfr[n], acc[m][n], 0, 0, 0);

        if (kt + 1 < NT) {
            short4v v0, v1;
            v0[0] = f2bf(a0[0]); v0[1] = f2bf(a0[1]); v0[2] = f2bf(a0[2]); v0[3] = f2bf(a0[3]);
            v1[0] = f2bf(a1[0]); v1[1] = f2bf(a1[1]); v1[2] = f2bf(a1[2]); v1[3] = f2bf(a1[3]);
            *(short4v*)((short*)As[cur ^ 1] + aoff0) = v0;
            *(short4v*)((short*)As[cur ^ 1] + aoff1) = v1;
            // drain B gloads + own LDS ops, then sync (fused: nothing slips between)
            asm volatile("s_waitcnt vmcnt(0) lgkmcnt(0)\n\ts_barrier" ::: "memory");
        }
    }
    #undef BSTAGE

    // ---- epilogue: partial score = sum over this wave's 128 cols of v[c]*tanh(q[b,c]+k)
    // C/D layout: col = lane&15, row = (lane>>4)*4 + reg
    const int bb = (int)(mbase >> 11);
    float qq[8], vv[8];
    #pragma unroll
    for (int n = 0; n < 8; ++n) {
        const int c = nbase + wc * 128 + n * 16 + frow;
        qq[n] = qv[bb * HD + c];
        vv[n] = ven[c];
    }
    float p[4][4];
    #pragma unroll
    for (int m = 0; m < 4; ++m) {
        #pragma unroll
        for (int rg = 0; rg < 4; ++rg) {
            float s = 0.f;
            #pragma unroll
            for (int n = 0; n < 8; ++n) {
                const float x = acc[m][n][rg] + qq[n];
                const float e = __expf(2.f * x);
                const float t = 1.f - 2.f * __builtin_amdgcn_rcpf(e + 1.f);
                s += vv[n] * t;
            }
            #pragma unroll
            for (int msk = 1; msk <= 8; msk <<= 1)
                s += __shfl_xor(s, msk, 64);   // reduce over 16-lane col group
            p[m][rg] = s;
        }
    }
    if ((lane & 15) == 0) {
        const int g = lane >> 4;
        float* dst = sp + (long)(nt * 4 + wc) * MM;   // 8 deterministic partial slots
        #pragma unroll
        for (int m = 0; m < 4; ++m)
            #pragma unroll
            for (int rg = 0; rg < 4; ++rg)
                dst[mbase + wr * 64 + m * 16 + g * 4 + rg] = p[m][rg];
    }
}

// ---------------- mask + softmax over S per batch ----------------
__global__ __launch_bounds__(256) void softmax_kernel(const float* __restrict__ sp,
                                                      const int* __restrict__ mask,
                                                      float* __restrict__ attn) {
    const int b = blockIdx.x;
    const int tid = threadIdx.x;
    const int lane = tid & 63;
    const int wid = tid >> 6;
    __shared__ float red[4];
    float sc[8];
    float mx = -3.0e38f;
    #pragma unroll
    for (int i = 0; i < 8; ++i) {
        const int s = tid + i * 256;
        float v = 0.f;
        #pragma unroll
        for (int k = 0; k < 8; ++k)
            v += sp[(long)k * MM + b * SS + s];
        if (mask[b * SS + s] == 0) v = -1e9f;
        sc[i] = v;
        mx = fmaxf(mx, v);
    }
    #pragma unroll
    for (int off = 32; off > 0; off >>= 1)
        mx = fmaxf(mx, __shfl_xor(mx, off, 64));
    if (lane == 0) red[wid] = mx;
    __syncthreads();
    mx = fmaxf(fmaxf(red[0], red[1]), fmaxf(red[2], red[3]));
    __syncthreads();
    float sum = 0.f;
    #pragma unroll
    for (int i = 0; i < 8; ++i) {
        const float e = __expf(sc[i] - mx);
        sc[i] = e;
        sum += e;
    }
    #pragma unroll
    for (int off = 32; off > 0; off >>= 1)
        sum += __shfl_xor(sum, off, 64);
    if (lane == 0) red[wid] = sum;
    __syncthreads();
    sum = red[0] + red[1] + red[2] + red[3];
    const float inv = 1.f / sum;
    #pragma unroll
    for (int i = 0; i < 8; ++i)
        attn[b * SS + tid + i * 256] = sc[i] * inv;
}

// ---------------- context: partial weighted sums over s-chunks (f32 enc) ----------------
__global__ __launch_bounds__(256) void ctx_partial_kernel(const float* __restrict__ enc,
                                                          const float* __restrict__ attn,
                                                          float* __restrict__ cp) {
    const int b = blockIdx.x >> 5;
    const int chunk = blockIdx.x & 31;
    const int tid = threadIdx.x;
    const float* ep = enc + ((long)b * SS + chunk * 64) * HE + tid * 4;
    const float* ap = attn + b * SS + chunk * 64;
    f32x4 acc = (f32x4){0.f, 0.f, 0.f, 0.f};
    #pragma unroll 4
    for (int s = 0; s < 64; ++s) {
        const float w = ap[s];
        const f32x4 v = *(const f32x4*)(ep + (long)s * HE);
        acc += w * v;
    }
    *(f32x4*)(cp + ((long)(b * 32 + chunk)) * HE + tid * 4) = acc;
}

__global__ __launch_bounds__(256) void ctx_reduce_kernel(const float* __restrict__ cp,
                                                         float* __restrict__ out) {
    const int o = blockIdx.x * 256 + threadIdx.x;
    const int b = o >> 10;
    const int e = o & 1023;
    float s = 0.f;
    #pragma unroll
    for (int c = 0; c < 32; ++c)
        s += cp[((long)(b * 32 + c)) * HE + e];
    out[o] = s;
}

extern "C" void kernel_launch(void* const* d_in, const int* in_sizes, int n_in,
                              void* d_out, int out_size, void* d_ws, size_t ws_size,
                              hipStream_t stream) {
    const float* dh   = (const float*)d_in[0];
    const float* enc  = (const float*)d_in[1];
    const int*   mask = (const int*)d_in[2];
    const float* Wq   = (const float*)d_in[3];
    const float* Wk   = (const float*)d_in[4];
    const float* Ve   = (const float*)d_in[5];

    float* out  = (float*)d_out;
    float* ctx  = out;
    float* attn = out + NB * HD;

    float* ws  = (float*)d_ws;
    float* wq_ = ws;                           // 32768 f
    float* sp  = ws + 32768;                   // 8 * 65536 f (2 MB)
    float* cp  = sp + 8 * (long)MM;            // 32*32*1024 f (4 MB)
    short* wkb = (short*)(cp + 32 * 32 * HE);  // 1M bf16 (2 MB)

    qproj_kernel<<<256, 256, 0, stream>>>(dh, Wq, wq_);
    cvt_bf16_kernel<<<512, 256, 0, stream>>>(Wk, wkb, HD * HE / 8);
    score_fused_kernel<<<1024, 512, 0, stream>>>(enc, wkb, wq_, Ve, sp);
    softmax_kernel<<<32, 256, 0, stream>>>(sp, mask, attn);
    ctx_partial_kernel<<<1024, 256, 0, stream>>>(enc, attn, cp);
    ctx_reduce_kernel<<<128, 256, 0, stream>>>(cp, ctx);
}